// Round 1
// baseline (1863.698 us; speedup 1.0000x reference)
//
#include <hip/hip_runtime.h>
#include <stdint.h>

// LoadingModel CAVI update: n=1000, p=50000, z=20, l=10 (fixed by setup_inputs).
// One persistent cooperative kernel; each thread owns one p-column; all carried
// state (W[z], ztx[z], Wk) lives in registers. Only cross-block communication:
// per-step softmax (max,sum) via tagged 64-bit slots (fused barrier+reduce).

#define NTHREADS 256
#define NBLK 196            // 196*256 = 50176 >= 50000
constexpr int N_DIM = 1000;
constexpr int P_DIM = 50000;
constexpr int Z_DIM = 20;
constexpr int L_DIM = 10;

using u64 = unsigned long long;

__device__ __forceinline__ float wred_max(float v) {
#pragma unroll
  for (int m = 32; m; m >>= 1) v = fmaxf(v, __shfl_xor(v, m, 64));
  return v;
}
__device__ __forceinline__ float wred_sum(float v) {
#pragma unroll
  for (int m = 32; m; m >>= 1) v += __shfl_xor(v, m, 64);
  return v;
}

__global__ __launch_bounds__(NTHREADS) void loading_model_kernel(
    const float* __restrict__ data,      // [n, p]
    const float* __restrict__ mean_z,    // [n, z]
    const float* __restrict__ mean_zz,   // [z, z]
    const float* __restrict__ mean_w_in, // [l, z, p]
    const float* __restrict__ alpha_in,  // [l, z, p]
    const float* __restrict__ tau_p,     // scalar
    const float* __restrict__ tau0,      // [l, z]
    const float* __restrict__ pi,        // [z, p]
    float* __restrict__ out_mw,          // [l, z, p]
    float* __restrict__ out_vw,          // [l, z]
    float* __restrict__ out_alpha,       // [l, z, p]
    u64* __restrict__ ws)                // slots: max[2][NBLK], sum[2][NBLK]
{
  const int tid  = threadIdx.x;
  const int blk  = blockIdx.x;
  const int gid  = blk * NTHREADS + tid;
  const bool active = (gid < P_DIM);
  const int lane = tid & 63;
  const int wid  = tid >> 6;
  const float tau = tau_p[0];

  __shared__ float lds_wmax[4];
  __shared__ float lds_wsum[4];

  // var_w output: fully determined by scalars, independent of the loop.
  if (blk == 0 && tid < L_DIM * Z_DIM) {
    int k = tid % Z_DIM;
    float E = mean_zz[k * Z_DIM + k];
    out_vw[tid] = 1.0f / (tau * E + tau0[tid]);
  }

  // ---- ZtX[k] = sum_n mean_z[n,k] * data[n, gid]  (mean_z via scalar loads) ----
  float ztx[Z_DIM];
#pragma unroll
  for (int k = 0; k < Z_DIM; k++) ztx[k] = 0.f;
  {
    const float* dcol = data + gid;
    for (int n = 0; n < N_DIM; n++) {
      float d = active ? dcol[(size_t)n * P_DIM] : 0.f;
#pragma unroll
      for (int k = 0; k < Z_DIM; k++) ztx[k] += mean_z[n * Z_DIM + k] * d;
    }
  }

  // ---- W[j] = sum_l mean_w[l,j,gid] * alpha[l,j,gid] ----
  float W[Z_DIM];
#pragma unroll
  for (int j = 0; j < Z_DIM; j++) W[j] = 0.f;
  for (int l = 0; l < L_DIM; l++) {
#pragma unroll
    for (int j = 0; j < Z_DIM; j++) {
      if (active) {
        size_t idx = ((size_t)(l * Z_DIM + j)) * P_DIM + gid;
        W[j] += mean_w_in[idx] * alpha_in[idx];
      }
    }
  }

  u64* slots_max = ws;            // [2][NBLK], tag<<32 | float bits
  u64* slots_sum = ws + 2 * NBLK; // [2][NBLK]

  float pival = active ? pi[gid] : 1.0f;
  float mw = 0.f, av = 0.f;
  if (active) { mw = mean_w_in[gid]; av = alpha_in[gid]; } // (l=0,k=0)

#pragma unroll
  for (int k = 0; k < Z_DIM; k++) {
    const float E    = mean_zz[k * Z_DIM + k];
    const float ktau = tau * E;
    const float s2   = 1.0f / ktau;
    const float zsc2 = tau / E;              // zs_scale^2 = (E*tau)/E^2

    float acc = 0.f;
#pragma unroll
    for (int j = 0; j < Z_DIM; j++) acc += mean_zz[k * Z_DIM + j] * W[j];
    const float RtZk = ztx[k] - (acc - E * W[k]);
    const float lpk  = active ? __logf(pival) : -INFINITY;
    if (k + 1 < Z_DIM && active) pival = pi[(size_t)(k + 1) * P_DIM + gid];

    float Wk = W[k];
    for (int l = 0; l < L_DIM; l++) {
      const float t0    = tau0[l * Z_DIM + k];
      const float s0inv = 1.0f / t0;
      const float s2p   = s2 + s0inv;
      const float c0    = 0.5f * (__logf(s2) - __logf(s2p));
      const float c1    = 0.5f * zsc2 * (s0inv / s2p);
      const float varn  = 1.0f / (ktau + t0);
      const float mnc   = tau * varn;

      const float Wkl = Wk - mw * av;
      const float E_R = RtZk - E * Wkl;
      float logit = lpk + c0 + c1 * E_R * E_R;
      if (!active) logit = -INFINITY;

      // Prefetch next step's mean_w/alpha: overlaps HBM latency with barrier.
      float mw_n = 0.f, av_n = 0.f;
      {
        int ln = l + 1, kn = k;
        if (ln == L_DIM) { ln = 0; kn = k + 1; }
        if (kn < Z_DIM && active) {
          size_t idx2 = ((size_t)(ln * Z_DIM + kn)) * P_DIM + gid;
          mw_n = mean_w_in[idx2];
          av_n = alpha_in[idx2];
        }
      }

      // ---- block-local softmax stats ----
      float wmax = wred_max(logit);
      if (lane == 0) lds_wmax[wid] = wmax;
      __syncthreads();
      float bmax = fmaxf(fmaxf(lds_wmax[0], lds_wmax[1]),
                         fmaxf(lds_wmax[2], lds_wmax[3]));
      float e = active ? __expf(logit - bmax) : 0.f;
      float wsum = wred_sum(e);
      if (lane == 0) lds_wsum[wid] = wsum;
      __syncthreads();

      const int s   = k * L_DIM + l + 1;   // step tag, 1..200
      const int buf = s & 1;
      if (tid == 0) {
        float bsum = lds_wsum[0] + lds_wsum[1] + lds_wsum[2] + lds_wsum[3];
        u64 tg = ((u64)(unsigned)s) << 32;
        __hip_atomic_store(&slots_max[buf * NBLK + blk],
                           tg | (u64)__float_as_uint(bmax),
                           __ATOMIC_RELAXED, __HIP_MEMORY_SCOPE_AGENT);
        __hip_atomic_store(&slots_sum[buf * NBLK + blk],
                           tg | (u64)__float_as_uint(bsum),
                           __ATOMIC_RELAXED, __HIP_MEMORY_SCOPE_AGENT);
      }

      // ---- fused barrier + global combine: every wave polls all slots ----
      float vmax[4], vsum[4];
#pragma unroll
      for (int q = 0; q < 4; q++) {
        int j = lane + (q << 6);
        if (j < NBLK) {
          u64 v;
          do {
            v = __hip_atomic_load(&slots_max[buf * NBLK + j],
                                  __ATOMIC_RELAXED, __HIP_MEMORY_SCOPE_AGENT);
          } while ((unsigned)(v >> 32) != (unsigned)s);
          vmax[q] = __uint_as_float((unsigned)v);
          do {
            v = __hip_atomic_load(&slots_sum[buf * NBLK + j],
                                  __ATOMIC_RELAXED, __HIP_MEMORY_SCOPE_AGENT);
          } while ((unsigned)(v >> 32) != (unsigned)s);
          vsum[q] = __uint_as_float((unsigned)v);
        } else {
          vmax[q] = -INFINITY;
          vsum[q] = 0.f;
        }
      }
      float M = fmaxf(fmaxf(vmax[0], vmax[1]), fmaxf(vmax[2], vmax[3]));
      M = wred_max(M);
      float ps = 0.f;
#pragma unroll
      for (int q = 0; q < 4; q++) ps += __expf(vmax[q] - M) * vsum[q];
      float S = wred_sum(ps);

      const float scale     = __expf(bmax - M) / S;
      const float alpha_new = e * scale;              // = exp(logit - M)/S
      const float mean_new  = mnc * E_R;
      Wk = Wkl + mean_new * alpha_new;

      if (active) {
        size_t oidx = ((size_t)(l * Z_DIM + k)) * P_DIM + gid;
        out_mw[oidx]    = mean_new;
        out_alpha[oidx] = alpha_new;
      }
      mw = mw_n;
      av = av_n;
    }
    W[k] = Wk;  // commit for subsequent factors' RtZk
  }
}

extern "C" void kernel_launch(void* const* d_in, const int* in_sizes, int n_in,
                              void* d_out, int out_size, void* d_ws, size_t ws_size,
                              hipStream_t stream) {
  const float* data    = (const float*)d_in[0];
  const float* mean_z  = (const float*)d_in[1];
  const float* mean_zz = (const float*)d_in[2];
  const float* mean_w  = (const float*)d_in[3];
  // d_in[4] = var_w (unused: fully overwritten)
  const float* alpha   = (const float*)d_in[5];
  const float* tau     = (const float*)d_in[6];
  const float* tau0    = (const float*)d_in[7];
  const float* pi      = (const float*)d_in[8];

  float* out_mw    = (float*)d_out;
  float* out_vw    = out_mw + (size_t)L_DIM * Z_DIM * P_DIM;
  float* out_alpha = out_vw + (size_t)L_DIM * Z_DIM;
  u64*   ws        = (u64*)d_ws;

  // Slots must not contain a valid step tag at start (harness poisons 0xAA,
  // which is safe, but zero them anyway for the first un-poisoned call).
  hipMemsetAsync(d_ws, 0, 4 * NBLK * sizeof(u64), stream);

  void* args[] = {(void*)&data, (void*)&mean_z, (void*)&mean_zz, (void*)&mean_w,
                  (void*)&alpha, (void*)&tau, (void*)&tau0, (void*)&pi,
                  (void*)&out_mw, (void*)&out_vw, (void*)&out_alpha, (void*)&ws};
  hipLaunchCooperativeKernel((void*)loading_model_kernel, dim3(NBLK),
                             dim3(NTHREADS), args, 0, stream);
}

// Round 2
// 1355.356 us; speedup vs baseline: 1.3751x; 1.3751x over previous
//
#include <hip/hip_runtime.h>
#include <stdint.h>

// LoadingModel CAVI update: n=1000, p=50000, z=20, l=10 (fixed by setup_inputs).
// Persistent cooperative kernel; each thread owns one p-column; carried state
// (W[z], ztx[z], Wk) in registers. Per-step global softmax via hierarchical
// tagged-LSE combine: block -> one tagged u64 (lse_b = bmax + log bsum);
// block0/wave0 combines all 196 -> one tagged result slot; others poll it.

#define NTHREADS 256
#define NBLK 196            // 196*256 = 50176 >= 50000
constexpr int N_DIM = 1000;
constexpr int P_DIM = 50000;
constexpr int Z_DIM = 20;
constexpr int L_DIM = 10;

using u64 = unsigned long long;

__device__ __forceinline__ float wred_max(float v) {
#pragma unroll
  for (int m = 32; m; m >>= 1) v = fmaxf(v, __shfl_xor(v, m, 64));
  return v;
}
__device__ __forceinline__ float wred_sum(float v) {
#pragma unroll
  for (int m = 32; m; m >>= 1) v += __shfl_xor(v, m, 64);
  return v;
}

__global__ __launch_bounds__(NTHREADS) void loading_model_kernel(
    const float* __restrict__ data,      // [n, p]
    const float* __restrict__ mean_z,    // [n, z]
    const float* __restrict__ mean_zz,   // [z, z]
    const float* __restrict__ mean_w_in, // [l, z, p]
    const float* __restrict__ alpha_in,  // [l, z, p]
    const float* __restrict__ tau_p,     // scalar
    const float* __restrict__ tau0,      // [l, z]
    const float* __restrict__ pi,        // [z, p]
    float* __restrict__ out_mw,          // [l, z, p]
    float* __restrict__ out_vw,          // [l, z]
    float* __restrict__ out_alpha,       // [l, z, p]
    u64* __restrict__ ws)                // slots[2][NBLK] + result[2]
{
  const int tid  = threadIdx.x;
  const int blk  = blockIdx.x;
  const int gid  = blk * NTHREADS + tid;
  const bool active = (gid < P_DIM);
  const int lane = tid & 63;
  const int wid  = tid >> 6;
  const float tau = tau_p[0];

  __shared__ float lds_wmax[4];
  __shared__ float lds_wsum[4];
  __shared__ float lds_lse;

  // var_w output: scalar-only, independent of the sequential loop.
  if (blk == 0 && tid < L_DIM * Z_DIM) {
    int k = tid % Z_DIM;
    float E = mean_zz[k * Z_DIM + k];
    out_vw[tid] = 1.0f / (tau * E + tau0[tid]);
  }

  // ---- ZtX[k] = sum_n mean_z[n,k] * data[n, gid] ----
  float ztx[Z_DIM];
#pragma unroll
  for (int k = 0; k < Z_DIM; k++) ztx[k] = 0.f;
  {
    const float* dcol = data + gid;
#pragma unroll 8
    for (int n = 0; n < N_DIM; n++) {
      float d = active ? dcol[(size_t)n * P_DIM] : 0.f;
#pragma unroll
      for (int k = 0; k < Z_DIM; k++) ztx[k] += mean_z[n * Z_DIM + k] * d;
    }
  }

  // ---- W[j] = sum_l mean_w[l,j,gid] * alpha[l,j,gid] ----
  float W[Z_DIM];
#pragma unroll
  for (int j = 0; j < Z_DIM; j++) W[j] = 0.f;
  for (int l = 0; l < L_DIM; l++) {
#pragma unroll
    for (int j = 0; j < Z_DIM; j++) {
      if (active) {
        size_t idx = ((size_t)(l * Z_DIM + j)) * P_DIM + gid;
        W[j] += mean_w_in[idx] * alpha_in[idx];
      }
    }
  }

  u64* slots  = ws;            // [2][NBLK], tag<<32 | float bits (block lse)
  u64* result = ws + 2 * NBLK; // [2],       tag<<32 | float bits (global lse)

  float pival = active ? pi[gid] : 1.0f;
  float mw = 0.f, av = 0.f;
  if (active) { mw = mean_w_in[gid]; av = alpha_in[gid]; } // (l=0,k=0)

#pragma unroll
  for (int k = 0; k < Z_DIM; k++) {
    const float E    = mean_zz[k * Z_DIM + k];
    const float ktau = tau * E;
    const float s2   = 1.0f / ktau;
    const float zsc2 = tau / E;              // zs_scale^2

    float acc = 0.f;
#pragma unroll
    for (int j = 0; j < Z_DIM; j++) acc += mean_zz[k * Z_DIM + j] * W[j];
    const float RtZk = ztx[k] - (acc - E * W[k]);
    const float lpk  = active ? __logf(pival) : -INFINITY;
    if (k + 1 < Z_DIM && active) pival = pi[(size_t)(k + 1) * P_DIM + gid];

    float Wk = W[k];
    for (int l = 0; l < L_DIM; l++) {
      const float t0    = tau0[l * Z_DIM + k];
      const float s0inv = 1.0f / t0;
      const float s2p   = s2 + s0inv;
      const float c0    = 0.5f * (__logf(s2) - __logf(s2p));
      const float c1    = 0.5f * zsc2 * (s0inv / s2p);
      const float varn  = 1.0f / (ktau + t0);
      const float mnc   = tau * varn;

      const float Wkl = Wk - mw * av;
      const float E_R = RtZk - E * Wkl;
      const float mean_new = mnc * E_R;
      float logit = lpk + c0 + c1 * E_R * E_R;
      if (!active) logit = -INFINITY;

      const size_t oidx = ((size_t)(l * Z_DIM + k)) * P_DIM + gid;
      if (active) out_mw[oidx] = mean_new;   // store early: overlap with wait

      // Prefetch next step's mean_w/alpha: overlaps HBM latency with barrier.
      float mw_n = 0.f, av_n = 0.f;
      {
        int ln = l + 1, kn = k;
        if (ln == L_DIM) { ln = 0; kn = k + 1; }
        if (kn < Z_DIM && active) {
          size_t idx2 = ((size_t)(ln * Z_DIM + kn)) * P_DIM + gid;
          mw_n = mean_w_in[idx2];
          av_n = alpha_in[idx2];
        }
      }

      // ---- per-wave softmax stats ----
      float wmax = wred_max(logit);
      float ew   = active ? __expf(logit - wmax) : 0.f;
      float wsum = wred_sum(ew);
      if (lane == 0) { lds_wmax[wid] = wmax; lds_wsum[wid] = wsum; }
      __syncthreads();

      const int s   = k * L_DIM + l + 1;   // step tag, 1..200
      const int buf = s & 1;
      if (tid == 0) {
        float m0 = lds_wmax[0], m1 = lds_wmax[1];
        float m2 = lds_wmax[2], m3 = lds_wmax[3];
        float M4 = fmaxf(fmaxf(m0, m1), fmaxf(m2, m3));
        float S4 = __expf(m0 - M4) * lds_wsum[0] + __expf(m1 - M4) * lds_wsum[1]
                 + __expf(m2 - M4) * lds_wsum[2] + __expf(m3 - M4) * lds_wsum[3];
        float lse_b = M4 + __logf(S4);
        __hip_atomic_store(&slots[buf * NBLK + blk],
                           (((u64)(unsigned)s) << 32) | (u64)__float_as_uint(lse_b),
                           __ATOMIC_RELAXED, __HIP_MEMORY_SCOPE_AGENT);
      }

      if (wid == 0) {
        if (blk == 0) {
          // combiner: batched (non-dependent) polls of all 196 slots
          u64 raw[4];
          bool ok = false;
          while (!ok) {
            ok = true;
#pragma unroll
            for (int q = 0; q < 4; q++) {
              int j = lane + (q << 6);
              if (j < NBLK)
                raw[q] = __hip_atomic_load(&slots[buf * NBLK + j],
                                           __ATOMIC_RELAXED, __HIP_MEMORY_SCOPE_AGENT);
            }
#pragma unroll
            for (int q = 0; q < 4; q++) {
              int j = lane + (q << 6);
              if (j < NBLK && (unsigned)(raw[q] >> 32) != (unsigned)s) ok = false;
            }
          }
          float m = -INFINITY;
#pragma unroll
          for (int q = 0; q < 4; q++) {
            int j = lane + (q << 6);
            if (j < NBLK) m = fmaxf(m, __uint_as_float((unsigned)raw[q]));
          }
          float M = wred_max(m);
          float ps = 0.f;
#pragma unroll
          for (int q = 0; q < 4; q++) {
            int j = lane + (q << 6);
            if (j < NBLK) ps += __expf(__uint_as_float((unsigned)raw[q]) - M);
          }
          float S = wred_sum(ps);
          float LSE = M + __logf(S);
          if (lane == 0) {
            __hip_atomic_store(&result[buf],
                               (((u64)(unsigned)s) << 32) | (u64)__float_as_uint(LSE),
                               __ATOMIC_RELAXED, __HIP_MEMORY_SCOPE_AGENT);
            lds_lse = LSE;
          }
        } else if (lane == 0) {
          u64 v;
          do {
            v = __hip_atomic_load(&result[buf],
                                  __ATOMIC_RELAXED, __HIP_MEMORY_SCOPE_AGENT);
          } while ((unsigned)(v >> 32) != (unsigned)s);
          lds_lse = __uint_as_float((unsigned)v);
        }
      }
      __syncthreads();

      const float LSEt = lds_lse;
      const float alpha_new = active ? __expf(logit - LSEt) : 0.f;
      Wk = Wkl + mean_new * alpha_new;
      if (active) out_alpha[oidx] = alpha_new;
      mw = mw_n;
      av = av_n;
    }
    W[k] = Wk;  // commit for subsequent factors' RtZk
  }
}

extern "C" void kernel_launch(void* const* d_in, const int* in_sizes, int n_in,
                              void* d_out, int out_size, void* d_ws, size_t ws_size,
                              hipStream_t stream) {
  const float* data    = (const float*)d_in[0];
  const float* mean_z  = (const float*)d_in[1];
  const float* mean_zz = (const float*)d_in[2];
  const float* mean_w  = (const float*)d_in[3];
  // d_in[4] = var_w (unused: fully overwritten)
  const float* alpha   = (const float*)d_in[5];
  const float* tau     = (const float*)d_in[6];
  const float* tau0    = (const float*)d_in[7];
  const float* pi      = (const float*)d_in[8];

  float* out_mw    = (float*)d_out;
  float* out_vw    = out_mw + (size_t)L_DIM * Z_DIM * P_DIM;
  float* out_alpha = out_vw + (size_t)L_DIM * Z_DIM;
  u64*   ws        = (u64*)d_ws;

  // Clear tags (poison 0xAA is also safe — tag never matches 1..200 — but the
  // memset is captured in the graph so every replay starts clean).
  hipMemsetAsync(d_ws, 0, (2 * NBLK + 2) * sizeof(u64), stream);

  void* args[] = {(void*)&data, (void*)&mean_z, (void*)&mean_zz, (void*)&mean_w,
                  (void*)&alpha, (void*)&tau, (void*)&tau0, (void*)&pi,
                  (void*)&out_mw, (void*)&out_vw, (void*)&out_alpha, (void*)&ws};
  hipLaunchCooperativeKernel((void*)loading_model_kernel, dim3(NBLK),
                             dim3(NTHREADS), args, 0, stream);
}

// Round 3
// 1343.583 us; speedup vs baseline: 1.3871x; 1.0088x over previous
//
#include <hip/hip_runtime.h>
#include <stdint.h>

// LoadingModel CAVI update: n=1000, p=50000, z=20, l=10 (fixed by setup_inputs).
// Persistent cooperative kernel; each thread owns one p-column; carried state
// (W[z], ztx[z], Wk) in registers. Per-step global softmax via FLAT one-hop
// all-gather: each block publishes one tagged u64 (lse_b = bmax + log bsum);
// wave 0 of EVERY block batch-polls all 196 slots, combines via shuffles,
// broadcasts through LDS. No second hop, no single hot cache line.

#define NTHREADS 256
#define NBLK 196            // 196*256 = 50176 >= 50000
constexpr int N_DIM = 1000;
constexpr int P_DIM = 50000;
constexpr int Z_DIM = 20;
constexpr int L_DIM = 10;

using u64 = unsigned long long;

__device__ __forceinline__ float wred_max(float v) {
#pragma unroll
  for (int m = 32; m; m >>= 1) v = fmaxf(v, __shfl_xor(v, m, 64));
  return v;
}
__device__ __forceinline__ float wred_sum(float v) {
#pragma unroll
  for (int m = 32; m; m >>= 1) v += __shfl_xor(v, m, 64);
  return v;
}

__global__ __launch_bounds__(NTHREADS) void loading_model_kernel(
    const float* __restrict__ data,      // [n, p]
    const float* __restrict__ mean_z,    // [n, z]
    const float* __restrict__ mean_zz,   // [z, z]
    const float* __restrict__ mean_w_in, // [l, z, p]
    const float* __restrict__ alpha_in,  // [l, z, p]
    const float* __restrict__ tau_p,     // scalar
    const float* __restrict__ tau0,      // [l, z]
    const float* __restrict__ pi,        // [z, p]
    float* __restrict__ out_mw,          // [l, z, p]
    float* __restrict__ out_vw,          // [l, z]
    float* __restrict__ out_alpha,       // [l, z, p]
    u64* __restrict__ ws)                // slots[2][NBLK]
{
  const int tid  = threadIdx.x;
  const int blk  = blockIdx.x;
  const int gid  = blk * NTHREADS + tid;
  const bool active = (gid < P_DIM);
  const int lane = tid & 63;
  const int wid  = tid >> 6;
  const float tau = tau_p[0];

  __shared__ float lds_wmax[4];
  __shared__ float lds_wsum[4];
  __shared__ float lds_lse;

  // var_w output: scalar-only, independent of the sequential loop.
  if (blk == 0 && tid < L_DIM * Z_DIM) {
    int k = tid % Z_DIM;
    float E = mean_zz[k * Z_DIM + k];
    out_vw[tid] = 1.0f / (tau * E + tau0[tid]);
  }

  // ---- ZtX[k] = sum_n mean_z[n,k] * data[n, gid] ----
  float ztx[Z_DIM];
#pragma unroll
  for (int k = 0; k < Z_DIM; k++) ztx[k] = 0.f;
  {
    const float* dcol = data + gid;
#pragma unroll 8
    for (int n = 0; n < N_DIM; n++) {
      float d = active ? dcol[(size_t)n * P_DIM] : 0.f;
#pragma unroll
      for (int k = 0; k < Z_DIM; k++) ztx[k] += mean_z[n * Z_DIM + k] * d;
    }
  }

  // ---- W[j] = sum_l mean_w[l,j,gid] * alpha[l,j,gid] ----
  float W[Z_DIM];
#pragma unroll
  for (int j = 0; j < Z_DIM; j++) W[j] = 0.f;
  for (int l = 0; l < L_DIM; l++) {
#pragma unroll
    for (int j = 0; j < Z_DIM; j++) {
      if (active) {
        size_t idx = ((size_t)(l * Z_DIM + j)) * P_DIM + gid;
        W[j] += mean_w_in[idx] * alpha_in[idx];
      }
    }
  }

  u64* slots = ws;  // [2][NBLK], tag<<32 | float bits (block lse)

  float pival = active ? pi[gid] : 1.0f;
  float mw = 0.f, av = 0.f;
  if (active) { mw = mean_w_in[gid]; av = alpha_in[gid]; } // (l=0,k=0)

  // Step-constant prefetch: (c0, c1, mnc) for step (k,l) computed during the
  // PREVIOUS step's wait, keeping two __logf's off the critical path.
  const float E0    = mean_zz[0];
  const float ktau0 = tau * E0;
  float cs2   = 1.0f / ktau0;       // current k's s2
  float czsc2 = tau / E0;           // current k's zs_scale^2
  float nc0, nc1, nmnc;
  {
    const float t0    = tau0[0];
    const float s0inv = 1.0f / t0;
    const float s2p   = cs2 + s0inv;
    nc0  = 0.5f * (__logf(cs2) - __logf(s2p));
    nc1  = 0.5f * czsc2 * (s0inv / s2p);
    nmnc = tau / (ktau0 + t0);
  }

#pragma unroll
  for (int k = 0; k < Z_DIM; k++) {
    const float E    = mean_zz[k * Z_DIM + k];
    const float ktau = tau * E;

    float acc = 0.f;
#pragma unroll
    for (int j = 0; j < Z_DIM; j++) acc += mean_zz[k * Z_DIM + j] * W[j];
    const float RtZk = ztx[k] - (acc - E * W[k]);
    const float lpk  = active ? __logf(pival) : -INFINITY;
    if (k + 1 < Z_DIM && active) pival = pi[(size_t)(k + 1) * P_DIM + gid];

    float Wk = W[k];
    for (int l = 0; l < L_DIM; l++) {
      const float c0  = nc0;
      const float c1  = nc1;
      const float mnc = nmnc;

      const float Wkl = Wk - mw * av;
      const float E_R = RtZk - E * Wkl;
      const float mean_new = mnc * E_R;
      float logit = lpk + c0 + c1 * E_R * E_R;
      if (!active) logit = -INFINITY;

      const size_t oidx = ((size_t)(l * Z_DIM + k)) * P_DIM + gid;
      if (active) out_mw[oidx] = mean_new;   // store early: overlap with wait

      // ---- per-wave softmax stats ----
      float wmax = wred_max(logit);
      float ew   = active ? __expf(logit - wmax) : 0.f;
      float wsum = wred_sum(ew);
      if (lane == 0) { lds_wmax[wid] = wmax; lds_wsum[wid] = wsum; }
      __syncthreads();

      const int s   = k * L_DIM + l + 1;   // step tag, 1..200
      const int buf = s & 1;
      if (tid == 0) {
        float m0 = lds_wmax[0], m1 = lds_wmax[1];
        float m2 = lds_wmax[2], m3 = lds_wmax[3];
        float M4 = fmaxf(fmaxf(m0, m1), fmaxf(m2, m3));
        float S4 = __expf(m0 - M4) * lds_wsum[0] + __expf(m1 - M4) * lds_wsum[1]
                 + __expf(m2 - M4) * lds_wsum[2] + __expf(m3 - M4) * lds_wsum[3];
        float lse_b = M4 + __logf(S4);
        __hip_atomic_store(&slots[buf * NBLK + blk],
                           (((u64)(unsigned)s) << 32) | (u64)__float_as_uint(lse_b),
                           __ATOMIC_RELAXED, __HIP_MEMORY_SCOPE_AGENT);
      }

      // ---- overlap with the wait: next step's mean_w/alpha + constants ----
      float mw_n = 0.f, av_n = 0.f;
      {
        int ln = l + 1, kn = k;
        if (ln == L_DIM) { ln = 0; kn = k + 1; }
        if (kn < Z_DIM) {
          if (active) {
            size_t idx2 = ((size_t)(ln * Z_DIM + kn)) * P_DIM + gid;
            mw_n = mean_w_in[idx2];
            av_n = alpha_in[idx2];
          }
          if (ln == 0) {  // entering next k: refresh per-k constants
            const float En = mean_zz[kn * Z_DIM + kn];
            const float kt = tau * En;
            cs2   = 1.0f / kt;
            czsc2 = tau / En;
          }
          const float t0n   = tau0[ln * Z_DIM + kn];
          const float s0inv = 1.0f / t0n;
          const float s2p   = cs2 + s0inv;
          nc0  = 0.5f * (__logf(cs2) - __logf(s2p));
          nc1  = 0.5f * czsc2 * (s0inv / s2p);
          nmnc = (ln == 0) ? tau / (tau * mean_zz[kn * Z_DIM + kn] + t0n)
                           : tau / (ktau + t0n);
        }
      }

      // ---- flat one-hop combine: wave 0 batch-polls all 196 slots ----
      if (wid == 0) {
        u64 raw[4];
        bool need[4];
#pragma unroll
        for (int q = 0; q < 4; q++) need[q] = (lane + (q << 6)) < NBLK;
        bool pend = true;
        while (pend) {
#pragma unroll
          for (int q = 0; q < 4; q++) {
            int j = lane + (q << 6);
            if (need[q])
              raw[q] = __hip_atomic_load(&slots[buf * NBLK + j],
                                         __ATOMIC_RELAXED, __HIP_MEMORY_SCOPE_AGENT);
          }
          pend = false;
#pragma unroll
          for (int q = 0; q < 4; q++) {
            if (need[q]) {
              if ((unsigned)(raw[q] >> 32) == (unsigned)s) need[q] = false;
              else pend = true;
            }
          }
        }
        float m = -INFINITY;
#pragma unroll
        for (int q = 0; q < 4; q++) {
          int j = lane + (q << 6);
          if (j < NBLK) m = fmaxf(m, __uint_as_float((unsigned)raw[q]));
        }
        float M = wred_max(m);
        float ps = 0.f;
#pragma unroll
        for (int q = 0; q < 4; q++) {
          int j = lane + (q << 6);
          if (j < NBLK) ps += __expf(__uint_as_float((unsigned)raw[q]) - M);
        }
        float S = wred_sum(ps);
        if (lane == 0) lds_lse = M + __logf(S);
      }
      __syncthreads();

      const float LSEt = lds_lse;
      const float alpha_new = active ? __expf(logit - LSEt) : 0.f;
      Wk = Wkl + mean_new * alpha_new;
      if (active) out_alpha[oidx] = alpha_new;
      mw = mw_n;
      av = av_n;
    }
    W[k] = Wk;  // commit for subsequent factors' RtZk
  }
}

extern "C" void kernel_launch(void* const* d_in, const int* in_sizes, int n_in,
                              void* d_out, int out_size, void* d_ws, size_t ws_size,
                              hipStream_t stream) {
  const float* data    = (const float*)d_in[0];
  const float* mean_z  = (const float*)d_in[1];
  const float* mean_zz = (const float*)d_in[2];
  const float* mean_w  = (const float*)d_in[3];
  // d_in[4] = var_w (unused: fully overwritten)
  const float* alpha   = (const float*)d_in[5];
  const float* tau     = (const float*)d_in[6];
  const float* tau0    = (const float*)d_in[7];
  const float* pi      = (const float*)d_in[8];

  float* out_mw    = (float*)d_out;
  float* out_vw    = out_mw + (size_t)L_DIM * Z_DIM * P_DIM;
  float* out_alpha = out_vw + (size_t)L_DIM * Z_DIM;
  u64*   ws        = (u64*)d_ws;

  // Clear tags (poison 0xAA is also tag-safe; memset keeps graph replays clean).
  hipMemsetAsync(d_ws, 0, 2 * NBLK * sizeof(u64), stream);

  void* args[] = {(void*)&data, (void*)&mean_z, (void*)&mean_zz, (void*)&mean_w,
                  (void*)&alpha, (void*)&tau, (void*)&tau0, (void*)&pi,
                  (void*)&out_mw, (void*)&out_vw, (void*)&out_alpha, (void*)&ws};
  hipLaunchCooperativeKernel((void*)loading_model_kernel, dim3(NBLK),
                             dim3(NTHREADS), args, 0, stream);
}